// Round 6
// baseline (217.568 us; speedup 1.0000x reference)
//
#include <hip/hip_runtime.h>

#define N_NODES 32768
#define N_EDGES 16384
#define DEG 4
#define KPE 8
#define DIM 128
#define EDIM 64
#define MAXC 64   // max containing-(node,slot) entries per edge; Poisson(8) -> P(>64) ~ 1e-40

typedef float f32x4 __attribute__((ext_vector_type(4)));
typedef __bf16 bf16x8 __attribute__((ext_vector_type(8)));
typedef __bf16 bf16x2 __attribute__((ext_vector_type(2)));
typedef unsigned short u16x8 __attribute__((ext_vector_type(8)));
typedef unsigned int u32;
typedef unsigned int u32x4 __attribute__((ext_vector_type(4)));
typedef int i32x4 __attribute__((ext_vector_type(4)));

static __device__ __forceinline__ unsigned short f2bf(float f) {
  union { float f; unsigned int u; } v; v.f = f;
  unsigned int r = (v.u + 0x7FFFu + ((v.u >> 16) & 1u)) >> 16;
  return (unsigned short)r;
}
static __device__ __forceinline__ float bflo(unsigned int v) {
  union { unsigned int u; float f; } x; x.u = v << 16; return x.f;
}
static __device__ __forceinline__ float bfhi(unsigned int v) {
  union { unsigned int u; float f; } x; x.u = v & 0xffff0000u; return x.f;
}
static __device__ __forceinline__ float f16tof(unsigned short h) {
  return (float)__builtin_bit_cast(_Float16, h);
}
static __device__ __forceinline__ unsigned short ftof16(float f) {
  return __builtin_bit_cast(unsigned short, (_Float16)f);
}

#if __has_builtin(__builtin_amdgcn_fdot2_f32_bf16)
static __device__ __forceinline__ float dot2bf(unsigned int a, unsigned int b, float c) {
  return __builtin_amdgcn_fdot2_f32_bf16(
      __builtin_bit_cast(bf16x2, a), __builtin_bit_cast(bf16x2, b), c, false);
}
#else
static __device__ __forceinline__ float dot2bf(unsigned int a, unsigned int b, float c) {
  c = fmaf(bflo(a), bflo(b), c);
  return fmaf(bfhi(a), bfhi(b), c);
}
#endif

// ---------------- zero the per-edge counters (must precede wprep atomics) -----
__global__ __launch_bounds__(256) void zcnt_kernel(int* __restrict__ cnt)
{
  cnt[blockIdx.x * 256 + threadIdx.x] = 0;
}

// ---------------- weight combine + reverse-CSR build --------------------------
// CW=[0.25*Wq@Wlin; Wk@Wlin; Wv@Wlin], CWE=Wk@Wedge, Wob=bf16(Wo).
// rev[e][0..cnt[e]) = packed (n*4+d) for every (n,d) with node_edges[n][d]==e.
// Slot order is atomic-nondeterministic but each entry writes its own (n,d)
// output slot downstream, so results are order-independent.
__global__ __launch_bounds__(256) void wprep_kernel(
    const float* __restrict__ Wq, const float* __restrict__ Wk,
    const float* __restrict__ Wv, const float* __restrict__ Wlin,
    const float* __restrict__ Wedge, const float* __restrict__ Wo,
    const int* __restrict__ node_edges,
    unsigned short* __restrict__ CW, unsigned short* __restrict__ CWE,
    unsigned short* __restrict__ Wob, int* __restrict__ cnt, int* __restrict__ rev)
{
  int id = blockIdx.x * 256 + threadIdx.x;
  if (id < 384 * 128) {
    int j = id >> 7, i = id & 127;
    const float* wrow; float scale = 1.0f;
    if (j < 128)      { wrow = Wq + j * 128; scale = 0.25f; }
    else if (j < 256) { wrow = Wk + (j - 128) * 128; }
    else              { wrow = Wv + (j - 256) * 128; }
    float s = 0.f;
    #pragma unroll 8
    for (int m = 0; m < 128; ++m) s += wrow[m] * Wlin[m * 128 + i];
    CW[id] = f2bf(s * scale);
  } else if (id < 384 * 128 + 128 * 64) {
    int id2 = id - 384 * 128; int j = id2 >> 6, t = id2 & 63;
    float s = 0.f;
    #pragma unroll 8
    for (int m = 0; m < 128; ++m) s += Wk[j * 128 + m] * Wedge[m * 64 + t];
    CWE[id2] = f2bf(s);
  } else if (id < 384 * 128 + 128 * 64 + 128 * 128) {
    int id3 = id - (384 * 128 + 128 * 64);
    Wob[id3] = f2bf(Wo[id3]);
  } else {
    int t = id - (384 * 128 + 128 * 64 + 128 * 128);   // t = n*DEG + d
    if (t < N_NODES * DEG) {
      int e = node_edges[t];
      int pos = atomicAdd(&cnt[e], 1);
      if (pos < MAXC) rev[(size_t)e * MAXC + pos] = t;
    }
  }
}

// ---------------- G12: fused g1 + g2 ------------------------------------------
// r10: OPERAND-SWAPPED MFMA (acc = mfma(bu, av)) computes D^T, so each lane's
// 4 acc regs are 4 CONSECUTIVE OUTPUT COLUMNS of one row -> one 8 B store
// replaces four scattered 2 B stores (96 -> 24 stores/lane). Bias becomes a
// per-lane float4 load. Math is bit-identical (same dot products).
__global__ __launch_bounds__(256) void g12_kernel(
    const float* __restrict__ x, const unsigned short* __restrict__ CW,
    const float* __restrict__ bq, const float* __restrict__ bv,
    unsigned short* __restrict__ qb, unsigned short* __restrict__ Kb,
    unsigned short* __restrict__ Vb,
    const float* __restrict__ ea, const unsigned short* __restrict__ CWE,
    const float* __restrict__ bk, unsigned short* __restrict__ WeKb)
{
  const int wave = threadIdx.x >> 6, lane = threadIdx.x & 63;
  const int r16 = lane & 15, quad = lane >> 4;

  if (blockIdx.x < 512) {
    const int m0 = blockIdx.x * 64 + wave * 16;
    u16x8 av[4];
    const float* arow = x + (size_t)(m0 + r16) * DIM + quad * 8;
    #pragma unroll
    for (int kk = 0; kk < 4; ++kk) {
      float4 a0 = *(const float4*)(arow + kk * 32);
      float4 a1 = *(const float4*)(arow + kk * 32 + 4);
      u16x8 au;
      au[0] = f2bf(a0.x); au[1] = f2bf(a0.y); au[2] = f2bf(a0.z); au[3] = f2bf(a0.w);
      au[4] = f2bf(a1.x); au[5] = f2bf(a1.y); au[6] = f2bf(a1.z); au[7] = f2bf(a1.w);
      av[kk] = au;
    }
    #pragma unroll
    for (int g = 0; g < 6; ++g) {
      f32x4 acc[4];
      const f32x4 z = {0.f, 0.f, 0.f, 0.f};
      acc[0] = z; acc[1] = z; acc[2] = z; acc[3] = z;
      #pragma unroll
      for (int kk = 0; kk < 4; ++kk) {
        #pragma unroll
        for (int s = 0; s < 4; ++s) {
          u16x8 bu = *(const u16x8*)(CW + (size_t)(g * 64 + s * 16 + r16) * DIM + kk * 32 + quad * 8);
          // swapped: D^T -> lane owns 4 consecutive cols of row m0+r16
          acc[s] = __builtin_amdgcn_mfma_f32_16x16x32_bf16(
              __builtin_bit_cast(bf16x8, bu), __builtin_bit_cast(bf16x8, av[kk]), acc[s], 0, 0, 0);
        }
      }
      const int arr = g >> 1;               // 0:q 1:K 2:V
      const int colbase = (g & 1) * 64;
      unsigned short* dst = arr == 0 ? qb : (arr == 1 ? Kb : Vb);
      const int m = m0 + r16;
      #pragma unroll
      for (int s = 0; s < 4; ++s) {
        const int j0 = colbase + s * 16 + quad * 4;
        float4 b4 = {0.f, 0.f, 0.f, 0.f};
        if (arr == 0) {
          float4 t = *(const float4*)(bq + j0);
          b4.x = 0.25f * t.x; b4.y = 0.25f * t.y; b4.z = 0.25f * t.z; b4.w = 0.25f * t.w;
        } else if (arr == 2) {
          b4 = *(const float4*)(bv + j0);
        }
        u32 lo = (u32)f2bf(acc[s][0] + b4.x) | ((u32)f2bf(acc[s][1] + b4.y) << 16);
        u32 hi = (u32)f2bf(acc[s][2] + b4.z) | ((u32)f2bf(acc[s][3] + b4.w) << 16);
        uint2 st = {lo, hi};
        *(uint2*)(dst + (size_t)m * DIM + j0) = st;
      }
    }
  } else {
    const int idx = blockIdx.x - 512;
    const int m0 = (idx >> 1) * 64 + wave * 16;
    const int n0 = (idx & 1) * 64;
    f32x4 acc[4];
    const f32x4 z = {0.f, 0.f, 0.f, 0.f};
    acc[0] = z; acc[1] = z; acc[2] = z; acc[3] = z;
    const float* arow = ea + (size_t)(m0 + r16) * EDIM + quad * 8;
    #pragma unroll
    for (int kk = 0; kk < 2; ++kk) {
      float4 a0 = *(const float4*)(arow + kk * 32);
      float4 a1 = *(const float4*)(arow + kk * 32 + 4);
      u16x8 au;
      au[0] = f2bf(a0.x); au[1] = f2bf(a0.y); au[2] = f2bf(a0.z); au[3] = f2bf(a0.w);
      au[4] = f2bf(a1.x); au[5] = f2bf(a1.y); au[6] = f2bf(a1.z); au[7] = f2bf(a1.w);
      bf16x8 av = __builtin_bit_cast(bf16x8, au);
      #pragma unroll
      for (int s = 0; s < 4; ++s) {
        u16x8 bu = *(const u16x8*)(CWE + (size_t)(n0 + s * 16 + r16) * EDIM + kk * 32 + quad * 8);
        acc[s] = __builtin_amdgcn_mfma_f32_16x16x32_bf16(
            __builtin_bit_cast(bf16x8, bu), av, acc[s], 0, 0, 0);
      }
    }
    const int m = m0 + r16;
    #pragma unroll
    for (int s = 0; s < 4; ++s) {
      const int j0 = n0 + s * 16 + quad * 4;
      float4 b4 = *(const float4*)(bk + j0);
      u32 lo = (u32)f2bf(acc[s][0] + b4.x) | ((u32)f2bf(acc[s][1] + b4.y) << 16);
      u32 hi = (u32)f2bf(acc[s][2] + b4.z) | ((u32)f2bf(acc[s][3] + b4.w) << 16);
      uint2 st = {lo, hi};
      *(uint2*)(WeKb + (size_t)m * DIM + j0) = st;
    }
  }
}

// ---------------- ESCORE: per-edge score kernel -------------------------------
// 1 wave = 1 edge. Lane = (member g = lane>>3, head j = lane&7). Each lane's
// 16-dim chunk IS head j -> a lane's local dot is a complete head score.
// r10: cnt[e] is WAVE-UNIFORM, so the c-loop batches 8 entries: all 16 q-loads
// issue up front (one L2/L3 round trip for the whole batch instead of ~8
// pipelined-by-1). Tail lanes clamp pk to 0 (harmless row-0 load, no store).
__global__ __launch_bounds__(256) void escore_kernel(
    const unsigned short* __restrict__ qb, const unsigned short* __restrict__ Kb,
    const unsigned short* __restrict__ WeKb, const int* __restrict__ enodes,
    const int* __restrict__ cnt, const int* __restrict__ rev,
    unsigned short* __restrict__ S)
{
  const int wave = threadIdx.x >> 6, lane = threadIdx.x & 63;
  const int e = blockIdx.x * 4 + wave;
  const int g = lane >> 3, j = lane & 7;

  int c_n = cnt[e]; if (c_n > MAXC) c_n = MAXC;
  if (c_n == 0) return;
  int rv = rev[(size_t)e * MAXC + lane];

  int mid = enodes[(size_t)e * KPE + g];
  u32x4 k0 = *(const u32x4*)(Kb + (size_t)mid * DIM + j * 16);
  u32x4 k1 = *(const u32x4*)(Kb + (size_t)mid * DIM + j * 16 + 8);
  u32x4 w0 = *(const u32x4*)(WeKb + (size_t)e * DIM + j * 16);
  u32x4 w1 = *(const u32x4*)(WeKb + (size_t)e * DIM + j * 16 + 8);

  for (int base = 0; base < c_n; base += 8) {
    int pks[8];
    u32x4 q0[8], q1[8];
    #pragma unroll
    for (int i = 0; i < 8; ++i) {
      int pk = __shfl(rv, base + i);
      pks[i] = (base + i < c_n) ? pk : 0;
      const unsigned short* qr = qb + (size_t)(pks[i] >> 2) * DIM + j * 16;
      q0[i] = *(const u32x4*)qr;
      q1[i] = *(const u32x4*)(qr + 8);
    }
    #pragma unroll
    for (int i = 0; i < 8; ++i) {
      if (base + i < c_n) {                      // wave-uniform, no divergence
        float s = 0.f;
        s = dot2bf(q0[i].x, k0.x, s); s = dot2bf(q0[i].y, k0.y, s);
        s = dot2bf(q0[i].z, k0.z, s); s = dot2bf(q0[i].w, k0.w, s);
        s = dot2bf(q1[i].x, k1.x, s); s = dot2bf(q1[i].y, k1.y, s);
        s = dot2bf(q1[i].z, k1.z, s); s = dot2bf(q1[i].w, k1.w, s);
        s = dot2bf(q0[i].x, w0.x, s); s = dot2bf(q0[i].y, w0.y, s);
        s = dot2bf(q0[i].z, w0.z, s); s = dot2bf(q0[i].w, w0.w, s);
        s = dot2bf(q1[i].x, w1.x, s); s = dot2bf(q1[i].y, w1.y, s);
        s = dot2bf(q1[i].z, w1.z, s); s = dot2bf(q1[i].w, w1.w, s);
        // S[n][key=d*8+g][head=j]: flat ushort idx = n*256 + d*64 + g*8 + j
        S[(size_t)(pks[i] >> 2) * 256 + (pks[i] & 3) * 64 + g * 8 + j] = ftof16(s);
      }
    }
  }
}

// ---------------- NSM: per-node softmax, S[n][l][h] -> P[n][h][l] in place ----
__global__ __launch_bounds__(256) void nsm_kernel(unsigned short* __restrict__ SP)
{
  const int wave = threadIdx.x >> 6, lane = threadIdx.x & 63;
  const int n = blockIdx.x * 4 + wave;
  const int l = lane & 31, hp = lane >> 5;
  unsigned short* row = SP + (size_t)n * 256;

  uint2 sv = *(const uint2*)(row + l * 8 + hp * 4);
  float s4[4] = { f16tof(sv.x & 0xffff), f16tof(sv.x >> 16),
                  f16tof(sv.y & 0xffff), f16tof(sv.y >> 16) };
  unsigned short pr[4];
  #pragma unroll
  for (int hi = 0; hi < 4; ++hi) {
    float vmax = s4[hi];
    #pragma unroll
    for (int off = 16; off >= 1; off >>= 1)
      vmax = fmaxf(vmax, __shfl_xor(vmax, off, 32));
    float ex = __expf(s4[hi] - vmax);
    float sum = ex;
    #pragma unroll
    for (int off = 16; off >= 1; off >>= 1)
      sum += __shfl_xor(sum, off, 32);
    pr[hi] = ftof16(ex / sum);
  }
  #pragma unroll
  for (int hi = 0; hi < 4; ++hi)
    row[(hp * 4 + hi) * 32 + l] = pr[hi];
}

// ---------------- ECTX: per-edge context partials -----------------------------
// 1 wave = 1 edge. Lane = dim pair (c0 = lane*2, head h = lane>>3).
// r10: same batch-of-8 prefetch of the P gathers as escore.
__global__ __launch_bounds__(256) void ectx_kernel(
    const unsigned short* __restrict__ Vb, const unsigned short* __restrict__ P,
    const int* __restrict__ enodes, const int* __restrict__ cnt,
    const int* __restrict__ rev, unsigned short* __restrict__ ctxp)
{
  const int wave = threadIdx.x >> 6, lane = threadIdx.x & 63;
  const int e = blockIdx.x * 4 + wave;
  const int c0 = lane * 2, h = lane >> 3;

  int c_n = cnt[e]; if (c_n > MAXC) c_n = MAXC;
  if (c_n == 0) return;
  int rv = rev[(size_t)e * MAXC + lane];

  const int* ep = enodes + (size_t)e * KPE;
  i32x4 a4 = *(const i32x4*)ep;
  i32x4 b4 = *(const i32x4*)(ep + 4);
  int id[8] = {a4.x, a4.y, a4.z, a4.w, b4.x, b4.y, b4.z, b4.w};
  u32 vv[8];
  #pragma unroll
  for (int k = 0; k < 8; ++k) vv[k] = *(const u32*)(Vb + (size_t)id[k] * DIM + c0);

  for (int base = 0; base < c_n; base += 8) {
    int pks[8];
    uint4 pv[8];
    #pragma unroll
    for (int i = 0; i < 8; ++i) {
      int pk = __shfl(rv, base + i);
      pks[i] = (base + i < c_n) ? pk : 0;
      pv[i] = *(const uint4*)(P + (size_t)(pks[i] >> 2) * 256 + h * 32 + (pks[i] & 3) * 8);
    }
    #pragma unroll
    for (int i = 0; i < 8; ++i) {
      if (base + i < c_n) {                      // wave-uniform
        float p0 = f16tof(pv[i].x & 0xffff), p1 = f16tof(pv[i].x >> 16);
        float p2 = f16tof(pv[i].y & 0xffff), p3 = f16tof(pv[i].y >> 16);
        float p4 = f16tof(pv[i].z & 0xffff), p5 = f16tof(pv[i].z >> 16);
        float p6 = f16tof(pv[i].w & 0xffff), p7 = f16tof(pv[i].w >> 16);
        float a0 = 0.f, a1 = 0.f;
        a0 = fmaf(p0, bflo(vv[0]), a0); a1 = fmaf(p0, bfhi(vv[0]), a1);
        a0 = fmaf(p1, bflo(vv[1]), a0); a1 = fmaf(p1, bfhi(vv[1]), a1);
        a0 = fmaf(p2, bflo(vv[2]), a0); a1 = fmaf(p2, bfhi(vv[2]), a1);
        a0 = fmaf(p3, bflo(vv[3]), a0); a1 = fmaf(p3, bfhi(vv[3]), a1);
        a0 = fmaf(p4, bflo(vv[4]), a0); a1 = fmaf(p4, bfhi(vv[4]), a1);
        a0 = fmaf(p5, bflo(vv[5]), a0); a1 = fmaf(p5, bfhi(vv[5]), a1);
        a0 = fmaf(p6, bflo(vv[6]), a0); a1 = fmaf(p6, bfhi(vv[6]), a1);
        a0 = fmaf(p7, bflo(vv[7]), a0); a1 = fmaf(p7, bfhi(vv[7]), a1);
        u32 pk2 = (u32)ftof16(a0) | ((u32)ftof16(a1) << 16);
        *(u32*)(ctxp + ((size_t)(pks[i] >> 2) * 4 + (pks[i] & 3)) * DIM + c0) = pk2;
      }
    }
  }
}

// ---------------- G4: (sum of 4 fp16 partials) @ Wo^T + bo, ReLU --------------
// r10: operand-swapped MFMA -> lane owns 4 consecutive out columns = float4 store.
__global__ __launch_bounds__(256) void g4_kernel(
    const unsigned short* __restrict__ ctxp, const unsigned short* __restrict__ Wob,
    const float* __restrict__ bo, float* __restrict__ out)
{
  const int wave = threadIdx.x >> 6, lane = threadIdx.x & 63;
  const int r16 = lane & 15, quad = lane >> 4;
  const int m0 = blockIdx.x * 64 + wave * 16;

  f32x4 acc[2][4];
  const f32x4 z = {0.f, 0.f, 0.f, 0.f};
  #pragma unroll
  for (int hf = 0; hf < 2; ++hf) { acc[hf][0] = z; acc[hf][1] = z; acc[hf][2] = z; acc[hf][3] = z; }

  #pragma unroll
  for (int kk = 0; kk < 4; ++kk) {
    float fa[8] = {0.f, 0.f, 0.f, 0.f, 0.f, 0.f, 0.f, 0.f};
    #pragma unroll
    for (int d = 0; d < 4; ++d) {
      u16x8 t = *(const u16x8*)(ctxp + ((size_t)(m0 + r16) * 4 + d) * DIM + kk * 32 + quad * 8);
      #pragma unroll
      for (int i = 0; i < 8; ++i) fa[i] += f16tof(t[i]);
    }
    u16x8 au;
    #pragma unroll
    for (int i = 0; i < 8; ++i) au[i] = f2bf(fa[i]);
    bf16x8 av = __builtin_bit_cast(bf16x8, au);
    #pragma unroll
    for (int hf = 0; hf < 2; ++hf) {
      #pragma unroll
      for (int s = 0; s < 4; ++s) {
        u16x8 bu = *(const u16x8*)(Wob + (size_t)(hf * 64 + s * 16 + r16) * DIM + kk * 32 + quad * 8);
        acc[hf][s] = __builtin_amdgcn_mfma_f32_16x16x32_bf16(
            __builtin_bit_cast(bf16x8, bu), av, acc[hf][s], 0, 0, 0);
      }
    }
  }

  const int m = m0 + r16;
  #pragma unroll
  for (int hf = 0; hf < 2; ++hf) {
    #pragma unroll
    for (int s = 0; s < 4; ++s) {
      const int j0 = hf * 64 + s * 16 + quad * 4;
      float4 b4 = *(const float4*)(bo + j0);
      float4 v;
      v.x = acc[hf][s][0] + b4.x; v.x = v.x > 0.f ? v.x : 0.f;
      v.y = acc[hf][s][1] + b4.y; v.y = v.y > 0.f ? v.y : 0.f;
      v.z = acc[hf][s][2] + b4.z; v.z = v.z > 0.f ? v.z : 0.f;
      v.w = acc[hf][s][3] + b4.w; v.w = v.w > 0.f ? v.w : 0.f;
      *(float4*)(out + (size_t)m * DIM + j0) = v;
    }
  }
}

extern "C" void kernel_launch(void* const* d_in, const int* in_sizes, int n_in,
                              void* d_out, int out_size, void* d_ws, size_t ws_size,
                              hipStream_t stream)
{
  const float* x     = (const float*)d_in[0];
  const float* ea    = (const float*)d_in[1];
  const int* nedges  = (const int*)d_in[2];
  const int* enodes  = (const int*)d_in[3];
  const float* Wlin  = (const float*)d_in[4];
  const float* Wedge = (const float*)d_in[5];
  const float* Wq    = (const float*)d_in[6];
  const float* Wk    = (const float*)d_in[7];
  const float* Wv    = (const float*)d_in[8];
  const float* bq    = (const float*)d_in[9];
  const float* bk    = (const float*)d_in[10];
  const float* bv    = (const float*)d_in[11];
  const float* Wo    = (const float*)d_in[12];
  const float* bo    = (const float*)d_in[13];
  float* out = (float*)d_out;

  unsigned short* wsp = (unsigned short*)d_ws;
  unsigned short* CW   = wsp;  wsp += 384 * 128;
  unsigned short* CWE  = wsp;  wsp += 128 * 64;
  unsigned short* Wob  = wsp;  wsp += 128 * 128;
  unsigned short* qb   = wsp;  wsp += (size_t)N_NODES * DIM;
  unsigned short* Kb   = wsp;  wsp += (size_t)N_NODES * DIM;
  unsigned short* Vb   = wsp;  wsp += (size_t)N_NODES * DIM;
  unsigned short* WeKb = wsp;  wsp += (size_t)N_EDGES * DIM;
  unsigned short* SP   = wsp;  wsp += (size_t)N_NODES * 256;      // fp16 S -> P in place (16 MB)
  unsigned short* ctxp = wsp;  wsp += (size_t)N_NODES * 4 * DIM;  // fp16 partials (33.5 MB)
  int* cnt = (int*)wsp;        wsp += N_EDGES * 2;
  int* rev = (int*)wsp;        wsp += (size_t)N_EDGES * MAXC * 2;

  zcnt_kernel<<<dim3(64), dim3(256), 0, stream>>>(cnt);
  wprep_kernel<<<dim3(800), dim3(256), 0, stream>>>(
      Wq, Wk, Wv, Wlin, Wedge, Wo, nedges, CW, CWE, Wob, cnt, rev);
  g12_kernel<<<dim3(1024), dim3(256), 0, stream>>>(x, CW, bq, bv, qb, Kb, Vb, ea, CWE, bk, WeKb);
  escore_kernel<<<dim3(N_EDGES / 4), dim3(256), 0, stream>>>(qb, Kb, WeKb, enodes, cnt, rev, SP);
  nsm_kernel<<<dim3(N_NODES / 4), dim3(256), 0, stream>>>(SP);
  ectx_kernel<<<dim3(N_EDGES / 4), dim3(256), 0, stream>>>(Vb, SP, enodes, cnt, rev, ctxp);
  g4_kernel<<<dim3(512), dim3(256), 0, stream>>>(ctxp, Wob, bo, out);
}